// Round 6
// baseline (21.532 us; speedup 1.0000x reference)
//
#include <hip/hip_runtime.h>

#define BATCH 128
#define DVAR  64
#define HDIM  128
#define NT    1024

typedef __attribute__((ext_vector_type(8))) __bf16 bf16x8;
typedef __attribute__((ext_vector_type(4))) float  f32x4;

__device__ __forceinline__ unsigned short f2bf(float f) {
    unsigned u = __float_as_uint(f);
    u += 0x7FFF + ((u >> 16) & 1);          // round-to-nearest-even
    return (unsigned short)(u >> 16);
}
__device__ __forceinline__ float bf2f(unsigned short b) {
    return __uint_as_float(((unsigned)b) << 16);
}
// tanh(x) = 1 - 2/(e^{2x}+1); err ~1e-5 << bf16 quant
__device__ __forceinline__ float fast_tanh(float x) {
    const float e = __expf(2.0f * x);
    return fmaf(-2.0f, __builtin_amdgcn_rcpf(e + 1.0f), 1.0f);
}

// ---------------- pre-pack: fp32 weights -> bf16 B-fragments in d_ws ----------------
// B-frag layout for mfma_f32_16x16x32_bf16: lane l supplies B[k=(l>>4)*8+e][col=l&15].
// sections: mw1 (K=256, KB=8) at 0; mw2 (K=128, KB=4) at 32768; dw1 (K=256, KB=8) at 49152.
__global__ void pack_w(const float* __restrict__ mw1, const float* __restrict__ mw2,
                       const float* __restrict__ dw1, unsigned short* __restrict__ ws) {
    int t = blockIdx.x * 256 + threadIdx.x;          // 0..10239
    const float* src; unsigned short* dst; int KB;
    if (t < 4096)      { src = mw1; dst = ws;         KB = 8; }
    else if (t < 6144) { src = mw2; dst = ws + 32768; KB = 4; t -= 4096; }
    else               { src = dw1; dst = ws + 49152; KB = 8; t -= 6144; }
    const int l  = t & 63, g = t >> 6;
    const int kb = g % KB, n = g / KB;
    const int k0  = kb * 32 + (l >> 4) * 8;
    const int col = n * 16 + (l & 15);
    unsigned short o[8];
    #pragma unroll
    for (int e = 0; e < 8; ++e) o[e] = f2bf(src[(k0 + e) * HDIM + col]);
    uint4 pk;
    unsigned short* pp = (unsigned short*)&pk;
    #pragma unroll
    for (int e = 0; e < 8; ++e) pp[e] = o[e];
    *(uint4*)(dst + (size_t)t * 8) = pk;             // coalesced 16B store
}

// ---------------- main fused kernel ----------------
// Grid 512 = (b = blockIdx>>1, i0 = (blockIdx&1)*32), 1024 threads = 16 waves,
// 2 blocks/CU (LDS ~74.6 KB), 8 waves/SIMD -> VGPR capped at 64.
__global__ __launch_bounds__(NT, 8) void gnn_fused(
    const float* __restrict__ X,  const float* __restrict__ W,
    const float* __restrict__ enc_w, const float* __restrict__ enc_b,
    const float* __restrict__ mb1, const float* __restrict__ mb2,
    const float* __restrict__ db1, const float* __restrict__ dw2,
    const float* __restrict__ db2,
    const unsigned short* __restrict__ ws,   // packed bf16 weights
    float* __restrict__ out)
{
    __shared__ unsigned short h_bf[DVAR * HDIM];   // 16.0 KB, XOR-swizzled (MFMA A)
    __shared__ unsigned short u_bf[DVAR * 130];    // 16.25 KB, padded, scalar access
    __shared__ float          v_f32[32 * 132];     // 16.5 KB, padded; reused as z
    __shared__ float          A_lds[DVAR][32];     // 8 KB
    __shared__ unsigned short r_bf[32 * HDIM];     // 8 KB, swizzled (MFMA A)
    __shared__ unsigned short agg_bf[32 * HDIM];   // 8 KB, swizzled (MFMA A)
    __shared__ float          Asum[32];

    const int tid  = threadIdx.x;
    const int b    = blockIdx.x >> 1;
    const int i0   = (blockIdx.x & 1) * 32;        // this block's i range [i0, i0+32)
    const int k    = tid & (HDIM - 1);
    const int g    = tid >> 7;          // 0..7, wave-uniform
    const int w    = tid >> 6;          // wave 0..15
    const int lane = tid & 63;
    const int lrow = lane & 15;
    const int lhi  = lane >> 4;

    const bf16x8* mw1p = (const bf16x8*)(const void*)(ws);
    const bf16x8* mw2p = (const bf16x8*)(const void*)(ws + 32768);
    const bf16x8* dw1p = (const bf16x8*)(const void*)(ws + 49152);

    // ---- P1: h = tanh(X*enc_w+enc_b) -> bf16 LDS (swizzled); stage A slab ----
    {
        const float ew = enc_w[k];
        const float eb = enc_b[k];
        #pragma unroll
        for (int m = 0; m < 8; ++m) {
            const int j = g + m * 8;                       // wave-uniform row
            h_bf[(j * HDIM + k) ^ ((j & 7) << 3)] = f2bf(fast_tanh(X[b * DVAR + j] * ew + eb));
        }
        #pragma unroll
        for (int m = 0; m < 2; ++m) {
            const int idx = tid + m * NT;                  // 0..2047
            const int j = idx >> 5, ii = idx & 31;
            A_lds[j][ii] = (j == i0 + ii) ? 0.0f : W[j * DVAR + i0 + ii];
        }
    }
    __syncthreads();
    if (tid < 32) {                                        // Asum[ii] = sum_j A[j,i]
        float s = 0.0f;
        for (int j = 0; j < DVAR; ++j) s += A_lds[j][tid];
        Asum[tid] = s;
    }

    // ---- P2 (MFMA, column-jobs): u[64][128] = h @ mw1[:H]; v[32][128] = h[i0:] @ mw1[H:]
    // 16 jobs: w<8 -> u-col ct=w (4 row-tiles); w>=8 -> v-col ct=w-8 (2 row-tiles).
    // Each B-frag loaded ONCE per block (reused across rt) -> minimal L2 traffic.
    {
        const bool isU = (w < 8);
        const int ct   = isU ? w : (w - 8);
        const int col  = ct * 16 + lrow;
        const int fb0  = ct * 8 + (isU ? 0 : 4);           // mw1 frag base (KB=8)
        f32x4 acc0 = {0.f,0.f,0.f,0.f}, acc1 = {0.f,0.f,0.f,0.f};
        f32x4 acc2 = {0.f,0.f,0.f,0.f}, acc3 = {0.f,0.f,0.f,0.f};
        #pragma unroll
        for (int kb = 0; kb < 4; ++kb) {
            const bf16x8 bb = mw1p[(fb0 + kb) * 64 + lane];
            const int koff = kb * 32 + lhi * 8;
            {   // rt = 0
                const int row = (isU ? 0 : i0) + lrow;
                const bf16x8 a = *(const bf16x8*)(const void*)(h_bf + ((row * HDIM + koff) ^ ((row & 7) << 3)));
                acc0 = __builtin_amdgcn_mfma_f32_16x16x32_bf16(a, bb, acc0, 0, 0, 0);
            }
            {   // rt = 1
                const int row = (isU ? 16 : i0 + 16) + lrow;
                const bf16x8 a = *(const bf16x8*)(const void*)(h_bf + ((row * HDIM + koff) ^ ((row & 7) << 3)));
                acc1 = __builtin_amdgcn_mfma_f32_16x16x32_bf16(a, bb, acc1, 0, 0, 0);
            }
            if (isU) {   // rt = 2,3 (u only)
                const int row2 = 32 + lrow;
                const bf16x8 a2 = *(const bf16x8*)(const void*)(h_bf + ((row2 * HDIM + koff) ^ ((row2 & 7) << 3)));
                acc2 = __builtin_amdgcn_mfma_f32_16x16x32_bf16(a2, bb, acc2, 0, 0, 0);
                const int row3 = 48 + lrow;
                const bf16x8 a3 = *(const bf16x8*)(const void*)(h_bf + ((row3 * HDIM + koff) ^ ((row3 & 7) << 3)));
                acc3 = __builtin_amdgcn_mfma_f32_16x16x32_bf16(a3, bb, acc3, 0, 0, 0);
            }
        }
        if (isU) {
            #pragma unroll
            for (int r = 0; r < 4; ++r) {
                u_bf[( 0 + lhi * 4 + r) * 130 + col] = f2bf(acc0[r]);
                u_bf[(16 + lhi * 4 + r) * 130 + col] = f2bf(acc1[r]);
                u_bf[(32 + lhi * 4 + r) * 130 + col] = f2bf(acc2[r]);
                u_bf[(48 + lhi * 4 + r) * 130 + col] = f2bf(acc3[r]);
            }
        } else {
            #pragma unroll
            for (int r = 0; r < 4; ++r) {
                v_f32[( 0 + lhi * 4 + r) * 132 + col] = acc0[r];
                v_f32[(16 + lhi * 4 + r) * 132 + col] = acc1[r];
            }
        }
    }
    __syncthreads();

    // ---- P3 (VALU): r[ii][k] = sum_j A[j][ii] * relu(u[j][k] + v[ii][k] + mb1[k]) ----
    {
        const float bk = mb1[k];
        float vvv[4];
        #pragma unroll
        for (int ii = 0; ii < 4; ++ii) vvv[ii] = v_f32[(g * 4 + ii) * 132 + k] + bk;
        float racc[4] = {0.f, 0.f, 0.f, 0.f};
        #pragma unroll 4
        for (int j = 0; j < DVAR; ++j) {
            const float uv = bf2f(u_bf[j * 130 + k]);
            const float4 a4 = *(const float4*)&A_lds[j][g * 4];   // wave-broadcast
            racc[0] = fmaf(fmaxf(uv + vvv[0], 0.f), a4.x, racc[0]);
            racc[1] = fmaf(fmaxf(uv + vvv[1], 0.f), a4.y, racc[1]);
            racc[2] = fmaf(fmaxf(uv + vvv[2], 0.f), a4.z, racc[2]);
            racc[3] = fmaf(fmaxf(uv + vvv[3], 0.f), a4.w, racc[3]);
        }
        #pragma unroll
        for (int ii = 0; ii < 4; ++ii) {
            const int row = g * 4 + ii;
            r_bf[(row * HDIM + k) ^ ((row & 7) << 3)] = f2bf(racc[ii]);
        }
    }
    __syncthreads();

    // ---- P4 (MFMA): agg[32][128] = r @ mw2 + Asum*mb2 -> bf16 LDS (swizzled) ----
    {
        const int rt = w >> 3, ct = w & 7;
        const int col = ct * 16 + lrow;
        f32x4 acc = {0.f, 0.f, 0.f, 0.f};
        #pragma unroll
        for (int kb = 0; kb < 4; ++kb) {
            const int row = rt * 16 + lrow;
            const int eidx = (row * HDIM + kb * 32 + lhi * 8) ^ ((row & 7) << 3);
            const bf16x8 a = *(const bf16x8*)(const void*)(r_bf + eidx);
            const bf16x8 bb = mw2p[(ct * 4 + kb) * 64 + lane];
            acc = __builtin_amdgcn_mfma_f32_16x16x32_bf16(a, bb, acc, 0, 0, 0);
        }
        const float m2 = mb2[col];
        #pragma unroll
        for (int r = 0; r < 4; ++r) {
            const int row = rt * 16 + lhi * 4 + r;
            agg_bf[(row * HDIM + col) ^ ((row & 7) << 3)] = f2bf(acc[r] + Asum[row] * m2);
        }
    }
    __syncthreads();

    // ---- P5 (MFMA, 8 ct-jobs): z = relu(h[i0:]@dw1[:H] + agg@dw1[H:] + db1) -> v_f32 ----
    if (w < 8) {
        const int ct = w;
        const int col = ct * 16 + lrow;
        f32x4 acc0 = {0.f,0.f,0.f,0.f}, acc1 = {0.f,0.f,0.f,0.f};
        #pragma unroll
        for (int kb = 0; kb < 4; ++kb) {               // h-half (dw1 rows 0..127)
            const bf16x8 bb = dw1p[(ct * 8 + kb) * 64 + lane];
            const int koff = kb * 32 + lhi * 8;
            const int row0 = i0 + lrow;
            const bf16x8 a0 = *(const bf16x8*)(const void*)(h_bf + ((row0 * HDIM + koff) ^ ((row0 & 7) << 3)));
            acc0 = __builtin_amdgcn_mfma_f32_16x16x32_bf16(a0, bb, acc0, 0, 0, 0);
            const int row1 = i0 + 16 + lrow;
            const bf16x8 a1 = *(const bf16x8*)(const void*)(h_bf + ((row1 * HDIM + koff) ^ ((row1 & 7) << 3)));
            acc1 = __builtin_amdgcn_mfma_f32_16x16x32_bf16(a1, bb, acc1, 0, 0, 0);
        }
        #pragma unroll
        for (int kb = 0; kb < 4; ++kb) {               // agg-half (dw1 rows 128..255)
            const bf16x8 bb = dw1p[(ct * 8 + 4 + kb) * 64 + lane];
            const int koff = kb * 32 + lhi * 8;
            const int row0 = lrow;
            const bf16x8 a0 = *(const bf16x8*)(const void*)(agg_bf + ((row0 * HDIM + koff) ^ ((row0 & 7) << 3)));
            acc0 = __builtin_amdgcn_mfma_f32_16x16x32_bf16(a0, bb, acc0, 0, 0, 0);
            const int row1 = 16 + lrow;
            const bf16x8 a1 = *(const bf16x8*)(const void*)(agg_bf + ((row1 * HDIM + koff) ^ ((row1 & 7) << 3)));
            acc1 = __builtin_amdgcn_mfma_f32_16x16x32_bf16(a1, bb, acc1, 0, 0, 0);
        }
        const float db = db1[col];
        #pragma unroll
        for (int r = 0; r < 4; ++r) {
            v_f32[( 0 + lhi * 4 + r) * 132 + col] = fmaxf(acc0[r] + db, 0.f);   // z
            v_f32[(16 + lhi * 4 + r) * 132 + col] = fmaxf(acc1[r] + db, 0.f);
        }
    }
    __syncthreads();

    // ---- P6: out[b][i0+row] = z[row] @ dw2 + db2 ----
    {
        const int row = tid >> 5;      // 0..31
        const int s   = tid & 31;
        float part = 0.0f;
        #pragma unroll
        for (int m = 0; m < 4; ++m) {
            const int kk = s + m * 32;
            part += v_f32[row * 132 + kk] * dw2[kk];
        }
        part += __shfl_xor(part, 1);
        part += __shfl_xor(part, 2);
        part += __shfl_xor(part, 4);
        part += __shfl_xor(part, 8);
        part += __shfl_xor(part, 16);
        if (s == 0) out[b * DVAR + i0 + row] = part + db2[0];
    }
}

extern "C" void kernel_launch(void* const* d_in, const int* in_sizes, int n_in,
                              void* d_out, int out_size, void* d_ws, size_t ws_size,
                              hipStream_t stream) {
    const float* X     = (const float*)d_in[0];
    const float* W     = (const float*)d_in[1];
    const float* enc_w = (const float*)d_in[2];
    const float* enc_b = (const float*)d_in[3];
    const float* mw1   = (const float*)d_in[4];
    const float* mb1   = (const float*)d_in[5];
    const float* mw2   = (const float*)d_in[6];
    const float* mb2   = (const float*)d_in[7];
    const float* dw1   = (const float*)d_in[8];
    const float* db1   = (const float*)d_in[9];
    const float* dw2   = (const float*)d_in[10];
    const float* db2   = (const float*)d_in[11];
    unsigned short* wsp = (unsigned short*)d_ws;

    pack_w<<<dim3(40), dim3(256), 0, stream>>>(mw1, mw2, dw1, wsp);
    gnn_fused<<<dim3(BATCH * 2), dim3(NT), 0, stream>>>(
        X, W, enc_w, enc_b, mb1, mb2, db1, dw2, db2, wsp, (float*)d_out);
}

// Round 7
// 18.381 us; speedup vs baseline: 1.1714x; 1.1714x over previous
//
#include <hip/hip_runtime.h>

#define BATCH 128
#define DVAR  64
#define HDIM  128
#define NT    1024

typedef __attribute__((ext_vector_type(8))) __bf16 bf16x8;
typedef __attribute__((ext_vector_type(4))) float  f32x4;

__device__ __forceinline__ unsigned short f2bf(float f) {
    unsigned u = __float_as_uint(f);
    u += 0x7FFF + ((u >> 16) & 1);          // round-to-nearest-even
    return (unsigned short)(u >> 16);
}
__device__ __forceinline__ float bf2f(unsigned short b) {
    return __uint_as_float(((unsigned)b) << 16);
}
// tanh(x) = 1 - 2/(e^{2x}+1); err ~1e-5 << bf16 quant
__device__ __forceinline__ float fast_tanh(float x) {
    const float e = __expf(2.0f * x);
    return fmaf(-2.0f, __builtin_amdgcn_rcpf(e + 1.0f), 1.0f);
}

// Gather one MFMA B-fragment (lane supplies B[kb*32+lhi*8+e][col], e=0..7) from a
// row-major fp32 [K][HDIM] matrix, converting to bf16 inline. 8 strided loads;
// 16 lanes/row read 64B contiguous; weights are L2-resident.
__device__ __forceinline__ bf16x8 ld_bfrag(const float* __restrict__ B, int kb, int lhi, int col) {
    const float* p = B + (kb * 32 + lhi * 8) * HDIM + col;
    union { bf16x8 v; unsigned short s[8]; } u;
    #pragma unroll
    for (int e = 0; e < 8; ++e) u.s[e] = f2bf(p[e * HDIM]);
    return u.v;
}

// ---------------- single fused kernel ----------------
// Grid 256 = (b = blockIdx>>1, i0 = (blockIdx&1)*32), 1024 threads = 16 waves.
__global__ __launch_bounds__(NT, 4) void gnn_fused(
    const float* __restrict__ X,  const float* __restrict__ W,
    const float* __restrict__ enc_w, const float* __restrict__ enc_b,
    const float* __restrict__ mw1, const float* __restrict__ mb1,
    const float* __restrict__ mw2, const float* __restrict__ mb2,
    const float* __restrict__ dw1, const float* __restrict__ db1,
    const float* __restrict__ dw2, const float* __restrict__ db2,
    float* __restrict__ out)
{
    __shared__ unsigned short h_bf[DVAR * HDIM];   // 16.0 KB, XOR-swizzled (MFMA A)
    __shared__ unsigned short u_bf[DVAR * 130];    // 16.25 KB, padded, scalar access
    __shared__ float          v_f32[32 * 132];     // 16.5 KB, padded; reused as z
    __shared__ float          A_lds[DVAR][32];     // 8 KB
    __shared__ unsigned short r_bf[32 * HDIM];     // 8 KB, swizzled (MFMA A)
    __shared__ unsigned short agg_bf[32 * HDIM];   // 8 KB, swizzled (MFMA A)
    __shared__ float          Asum[32];

    const int tid  = threadIdx.x;
    const int b    = blockIdx.x >> 1;
    const int i0   = (blockIdx.x & 1) * 32;        // this block's i range [i0, i0+32)
    const int k    = tid & (HDIM - 1);
    const int g    = tid >> 7;          // 0..7, wave-uniform
    const int w    = tid >> 6;          // wave 0..15
    const int lane = tid & 63;
    const int lrow = lane & 15;
    const int lhi  = lane >> 4;

    const float* mw1v = mw1 + HDIM * HDIM;   // mw1[H:] half
    const float* dw1a = dw1 + HDIM * HDIM;   // dw1[H:] half (agg side)

    // ---- P1: h = tanh(X*enc_w+enc_b) -> bf16 LDS (swizzled); stage A slab ----
    {
        const float ew = enc_w[k];
        const float eb = enc_b[k];
        #pragma unroll
        for (int m = 0; m < 8; ++m) {
            const int j = g + m * 8;                       // wave-uniform row
            h_bf[(j * HDIM + k) ^ ((j & 7) << 3)] = f2bf(fast_tanh(X[b * DVAR + j] * ew + eb));
        }
        #pragma unroll
        for (int m = 0; m < 2; ++m) {
            const int idx = tid + m * NT;                  // 0..2047
            const int j = idx >> 5, ii = idx & 31;
            A_lds[j][ii] = (j == i0 + ii) ? 0.0f : W[j * DVAR + i0 + ii];
        }
    }
    __syncthreads();
    if (tid < 32) {                                        // Asum[ii] = sum_j A[j,i]
        float s = 0.0f;
        for (int j = 0; j < DVAR; ++j) s += A_lds[j][tid];
        Asum[tid] = s;
    }

    // ---- P2 (MFMA, column-jobs):
    //   waves 0..7 : u[64][128] = h @ mw1[:H]          (ct=w, 4 row-tiles)
    //   waves 8..15: v[32][128] = h[i0:] @ mw1[H:]     (ct=w-8, 2 row-tiles)
    //              + zh[32][128] = h[i0:] @ dw1[:H]    (stashed in registers for P5)
    // Each B-frag gathered ONCE per block, reused across row-tiles.
    f32x4 zh0 = {0.f,0.f,0.f,0.f}, zh1 = {0.f,0.f,0.f,0.f};   // live P2 -> P5 (waves >= 8)
    {
        const bool isU = (w < 8);
        const int ct   = isU ? w : (w - 8);
        const int col  = ct * 16 + lrow;
        f32x4 acc0 = {0.f,0.f,0.f,0.f}, acc1 = {0.f,0.f,0.f,0.f};
        f32x4 acc2 = {0.f,0.f,0.f,0.f}, acc3 = {0.f,0.f,0.f,0.f};
        #pragma unroll
        for (int kb = 0; kb < 4; ++kb) {
            const int koff = kb * 32 + lhi * 8;
            if (isU) {
                const bf16x8 bb = ld_bfrag(mw1, kb, lhi, col);
                #pragma unroll
                for (int rt = 0; rt < 4; ++rt) {
                    const int row = rt * 16 + lrow;
                    const bf16x8 a = *(const bf16x8*)(const void*)(h_bf + ((row * HDIM + koff) ^ ((row & 7) << 3)));
                    f32x4& acc = rt == 0 ? acc0 : rt == 1 ? acc1 : rt == 2 ? acc2 : acc3;
                    acc = __builtin_amdgcn_mfma_f32_16x16x32_bf16(a, bb, acc, 0, 0, 0);
                }
            } else {
                const bf16x8 bbV = ld_bfrag(mw1v, kb, lhi, col);
                const bf16x8 bbZ = ld_bfrag(dw1,  kb, lhi, col);
                const int row0 = i0 + lrow;
                const bf16x8 a0 = *(const bf16x8*)(const void*)(h_bf + ((row0 * HDIM + koff) ^ ((row0 & 7) << 3)));
                const int row1 = i0 + 16 + lrow;
                const bf16x8 a1 = *(const bf16x8*)(const void*)(h_bf + ((row1 * HDIM + koff) ^ ((row1 & 7) << 3)));
                acc0 = __builtin_amdgcn_mfma_f32_16x16x32_bf16(a0, bbV, acc0, 0, 0, 0);
                acc1 = __builtin_amdgcn_mfma_f32_16x16x32_bf16(a1, bbV, acc1, 0, 0, 0);
                zh0  = __builtin_amdgcn_mfma_f32_16x16x32_bf16(a0, bbZ, zh0,  0, 0, 0);
                zh1  = __builtin_amdgcn_mfma_f32_16x16x32_bf16(a1, bbZ, zh1,  0, 0, 0);
            }
        }
        if (isU) {
            #pragma unroll
            for (int r = 0; r < 4; ++r) {
                u_bf[( 0 + lhi * 4 + r) * 130 + col] = f2bf(acc0[r]);
                u_bf[(16 + lhi * 4 + r) * 130 + col] = f2bf(acc1[r]);
                u_bf[(32 + lhi * 4 + r) * 130 + col] = f2bf(acc2[r]);
                u_bf[(48 + lhi * 4 + r) * 130 + col] = f2bf(acc3[r]);
            }
        } else {
            #pragma unroll
            for (int r = 0; r < 4; ++r) {
                v_f32[( 0 + lhi * 4 + r) * 132 + col] = acc0[r];
                v_f32[(16 + lhi * 4 + r) * 132 + col] = acc1[r];
            }
        }
    }
    __syncthreads();

    // ---- P3 (VALU): r[ii][k] = sum_j A[j][ii] * relu(u[j][k] + v[ii][k] + mb1[k]) ----
    {
        const float bk = mb1[k];
        float vvv[4];
        #pragma unroll
        for (int ii = 0; ii < 4; ++ii) vvv[ii] = v_f32[(g * 4 + ii) * 132 + k] + bk;
        float racc[4] = {0.f, 0.f, 0.f, 0.f};
        #pragma unroll 4
        for (int j = 0; j < DVAR; ++j) {
            const float uv = bf2f(u_bf[j * 130 + k]);
            const float4 a4 = *(const float4*)&A_lds[j][g * 4];   // wave-broadcast
            racc[0] = fmaf(fmaxf(uv + vvv[0], 0.f), a4.x, racc[0]);
            racc[1] = fmaf(fmaxf(uv + vvv[1], 0.f), a4.y, racc[1]);
            racc[2] = fmaf(fmaxf(uv + vvv[2], 0.f), a4.z, racc[2]);
            racc[3] = fmaf(fmaxf(uv + vvv[3], 0.f), a4.w, racc[3]);
        }
        #pragma unroll
        for (int ii = 0; ii < 4; ++ii) {
            const int row = g * 4 + ii;
            r_bf[(row * HDIM + k) ^ ((row & 7) << 3)] = f2bf(racc[ii]);
        }
    }
    __syncthreads();

    // ---- P4 (MFMA): agg[32][128] = r @ mw2 + Asum*mb2 -> bf16 LDS (swizzled) ----
    {
        const int rt = w >> 3, ct = w & 7;
        const int col = ct * 16 + lrow;
        f32x4 acc = {0.f, 0.f, 0.f, 0.f};
        #pragma unroll
        for (int kb = 0; kb < 4; ++kb) {
            const int row = rt * 16 + lrow;
            const int eidx = (row * HDIM + kb * 32 + lhi * 8) ^ ((row & 7) << 3);
            const bf16x8 a = *(const bf16x8*)(const void*)(r_bf + eidx);
            const bf16x8 bb = ld_bfrag(mw2, kb, lhi, col);
            acc = __builtin_amdgcn_mfma_f32_16x16x32_bf16(a, bb, acc, 0, 0, 0);
        }
        const float m2 = mb2[col];
        #pragma unroll
        for (int r = 0; r < 4; ++r) {
            const int row = rt * 16 + lhi * 4 + r;
            agg_bf[(row * HDIM + col) ^ ((row & 7) << 3)] = f2bf(acc[r] + Asum[row] * m2);
        }
    }
    __syncthreads();

    // ---- P5 (MFMA, waves 8..15): z = relu(zh + agg@dw1[H:] + db1) -> v_f32 (reused) ----
    if (w >= 8) {
        const int ct = w - 8;
        const int col = ct * 16 + lrow;
        f32x4 acc0 = zh0, acc1 = zh1;
        #pragma unroll
        for (int kb = 0; kb < 4; ++kb) {
            const bf16x8 bb = ld_bfrag(dw1a, kb, lhi, col);
            const int koff = kb * 32 + lhi * 8;
            const int row0 = lrow;
            const bf16x8 a0 = *(const bf16x8*)(const void*)(agg_bf + ((row0 * HDIM + koff) ^ ((row0 & 7) << 3)));
            acc0 = __builtin_amdgcn_mfma_f32_16x16x32_bf16(a0, bb, acc0, 0, 0, 0);
            const int row1 = 16 + lrow;
            const bf16x8 a1 = *(const bf16x8*)(const void*)(agg_bf + ((row1 * HDIM + koff) ^ ((row1 & 7) << 3)));
            acc1 = __builtin_amdgcn_mfma_f32_16x16x32_bf16(a1, bb, acc1, 0, 0, 0);
        }
        const float db = db1[col];
        #pragma unroll
        for (int r = 0; r < 4; ++r) {
            v_f32[( 0 + lhi * 4 + r) * 132 + col] = fmaxf(acc0[r] + db, 0.f);   // z
            v_f32[(16 + lhi * 4 + r) * 132 + col] = fmaxf(acc1[r] + db, 0.f);
        }
    }
    __syncthreads();

    // ---- P6: out[b][i0+row] = z[row] @ dw2 + db2 ----
    {
        const int row = tid >> 5;      // 0..31
        const int s   = tid & 31;
        float part = 0.0f;
        #pragma unroll
        for (int m = 0; m < 4; ++m) {
            const int kk = s + m * 32;
            part += v_f32[row * 132 + kk] * dw2[kk];
        }
        part += __shfl_xor(part, 1);
        part += __shfl_xor(part, 2);
        part += __shfl_xor(part, 4);
        part += __shfl_xor(part, 8);
        part += __shfl_xor(part, 16);
        if (s == 0) out[b * DVAR + i0 + row] = part + db2[0];
    }
}

extern "C" void kernel_launch(void* const* d_in, const int* in_sizes, int n_in,
                              void* d_out, int out_size, void* d_ws, size_t ws_size,
                              hipStream_t stream) {
    const float* X     = (const float*)d_in[0];
    const float* W     = (const float*)d_in[1];
    const float* enc_w = (const float*)d_in[2];
    const float* enc_b = (const float*)d_in[3];
    const float* mw1   = (const float*)d_in[4];
    const float* mb1   = (const float*)d_in[5];
    const float* mw2   = (const float*)d_in[6];
    const float* mb2   = (const float*)d_in[7];
    const float* dw1   = (const float*)d_in[8];
    const float* db1   = (const float*)d_in[9];
    const float* dw2   = (const float*)d_in[10];
    const float* db2   = (const float*)d_in[11];

    gnn_fused<<<dim3(BATCH * 2), dim3(NT), 0, stream>>>(
        X, W, enc_w, enc_b, mw1, mb1, mw2, mb2, dw1, db1, dw2, db2,
        (float*)d_out);
}

// Round 9
// 16.342 us; speedup vs baseline: 1.3176x; 1.1248x over previous
//
#include <hip/hip_runtime.h>

#define BATCH 128
#define DVAR  64
#define HDIM  128
#define NT    1024

typedef __attribute__((ext_vector_type(8))) __bf16    bf16x8;
typedef __attribute__((ext_vector_type(4))) float     f32x4;
typedef __attribute__((ext_vector_type(2))) _Float16  h2;

__device__ __forceinline__ unsigned short f2bf(float f) {
    unsigned u = __float_as_uint(f);
    u += 0x7FFF + ((u >> 16) & 1);          // round-to-nearest-even
    return (unsigned short)(u >> 16);
}
__device__ __forceinline__ h2 u2h(unsigned x) { union { unsigned u; h2 h; } c; c.u = x; return c.h; }
// v_cvt_pkrtz_f16_f32 returns a __fp16 vector; bit-cast to our _Float16 h2.
__device__ __forceinline__ h2 cvt_pk(float a, float b) {
    auto r = __builtin_amdgcn_cvt_pkrtz(a, b);
    union { decltype(r) f; h2 h; } c; c.f = r; return c.h;
}
// tanh(x) = 1 - 2/(e^{2x}+1); err ~1e-5 << fp16/bf16 quant
__device__ __forceinline__ float fast_tanh(float x) {
    const float e = __expf(2.0f * x);
    return fmaf(-2.0f, __builtin_amdgcn_rcpf(e + 1.0f), 1.0f);
}

// Gather one MFMA B-fragment (lane supplies B[kb*32+lhi*8+e][col]) from row-major
// fp32 [K][HDIM], converting to bf16 inline. Weights are L2-resident.
__device__ __forceinline__ bf16x8 ld_bfrag(const float* __restrict__ B, int kb, int lhi, int col) {
    const float* p = B + (kb * 32 + lhi * 8) * HDIM + col;
    union { bf16x8 v; unsigned short s[8]; } u;
    #pragma unroll
    for (int e = 0; e < 8; ++e) u.s[e] = f2bf(p[e * HDIM]);
    return u.v;
}

// ---------------- single fused kernel ----------------
// Grid 256 = (b = blockIdx>>1, i0 = (blockIdx&1)*32), 1024 threads = 16 waves.
__global__ __launch_bounds__(NT, 4) void gnn_fused(
    const float* __restrict__ X,  const float* __restrict__ W,
    const float* __restrict__ enc_w, const float* __restrict__ enc_b,
    const float* __restrict__ mw1, const float* __restrict__ mb1,
    const float* __restrict__ mw2, const float* __restrict__ mb2,
    const float* __restrict__ dw1, const float* __restrict__ db1,
    const float* __restrict__ dw2, const float* __restrict__ db2,
    float* __restrict__ out)
{
    __shared__ unsigned short h_bf[DVAR * HDIM];   // 16 KB, XOR-swizzled (MFMA A)
    __shared__ h2             u_pk[32 * 129];      // 16.1 KB: (u[2jp],u[2jp+1]) fp16 pairs
    __shared__ float          v_f32[32 * 132];     // 16.5 KB, padded; reused as z
    __shared__ h2             A_pk[32][32];        // 4 KB: (A[2jp][ii],A[2jp+1][ii]) fp16
    __shared__ unsigned short r_bf[32 * HDIM];     // 8 KB, swizzled (MFMA A)
    __shared__ unsigned short agg_bf[32 * HDIM];   // 8 KB, swizzled (MFMA A)
    __shared__ float          Asum[32];

    const int tid  = threadIdx.x;
    const int b    = blockIdx.x >> 1;
    const int i0   = (blockIdx.x & 1) * 32;        // this block's i range [i0, i0+32)
    const int k    = tid & (HDIM - 1);
    const int g    = tid >> 7;          // 0..7, wave-uniform
    const int w    = tid >> 6;          // wave 0..15
    const int lane = tid & 63;
    const int lrow = lane & 15;
    const int lhi  = lane >> 4;

    const float* mw1v = mw1 + HDIM * HDIM;   // mw1[H:]
    const float* dw1a = dw1 + HDIM * HDIM;   // dw1[H:] (agg side)

    // ---- P1: h = tanh(X*enc_w+enc_b) -> bf16 LDS (swizzled); stage A fp16 pairs ----
    {
        const float ew = enc_w[k];
        const float eb = enc_b[k];
        #pragma unroll
        for (int m = 0; m < 8; ++m) {
            const int j = g + m * 8;                       // wave-uniform row
            h_bf[(j * HDIM + k) ^ ((j & 7) << 3)] = f2bf(fast_tanh(X[b * DVAR + j] * ew + eb));
        }
        const int jp = tid >> 5, ii = tid & 31;            // 32 jp-pairs x 32 ii
        const int i  = i0 + ii;
        const int j0 = 2 * jp, j1 = 2 * jp + 1;
        const float a0 = (j0 == i) ? 0.f : W[j0 * DVAR + i];
        const float a1 = (j1 == i) ? 0.f : W[j1 * DVAR + i];
        A_pk[jp][ii] = cvt_pk(a0, a1);
    }
    __syncthreads();
    if (tid < 32) {                                        // Asum[ii] = sum_j A[j,i]
        float s = 0.f;
        for (int jp = 0; jp < 32; ++jp) {
            const h2 a = A_pk[jp][tid];
            s += (float)a.x + (float)a.y;
        }
        Asum[tid] = s;
    }

    // ---- P2 (MFMA, column-jobs):
    //   waves 0..7 : u[64][128] = h @ mw1[:H]        -> u_pk fp16 pairs
    //   waves 8..15: v[32][128] = h[i0:] @ mw1[H:]   -> v_f32
    //              + zh[32][128] = h[i0:] @ dw1[:H]  (stashed in registers for P5)
    f32x4 zh0 = {0.f,0.f,0.f,0.f}, zh1 = {0.f,0.f,0.f,0.f};   // live P2 -> P5 (waves >= 8)
    {
        const bool isU = (w < 8);
        const int ct   = isU ? w : (w - 8);
        const int col  = ct * 16 + lrow;
        f32x4 acc0 = {0.f,0.f,0.f,0.f}, acc1 = {0.f,0.f,0.f,0.f};
        f32x4 acc2 = {0.f,0.f,0.f,0.f}, acc3 = {0.f,0.f,0.f,0.f};
        #pragma unroll
        for (int kb = 0; kb < 4; ++kb) {
            const int koff = kb * 32 + lhi * 8;
            if (isU) {
                const bf16x8 bb = ld_bfrag(mw1, kb, lhi, col);
                #pragma unroll
                for (int rt = 0; rt < 4; ++rt) {
                    const int row = rt * 16 + lrow;
                    const bf16x8 a = *(const bf16x8*)(const void*)(h_bf + ((row * HDIM + koff) ^ ((row & 7) << 3)));
                    f32x4& acc = rt == 0 ? acc0 : rt == 1 ? acc1 : rt == 2 ? acc2 : acc3;
                    acc = __builtin_amdgcn_mfma_f32_16x16x32_bf16(a, bb, acc, 0, 0, 0);
                }
            } else {
                const bf16x8 bbV = ld_bfrag(mw1v, kb, lhi, col);
                const bf16x8 bbZ = ld_bfrag(dw1,  kb, lhi, col);
                const int row0 = i0 + lrow;
                const bf16x8 a0 = *(const bf16x8*)(const void*)(h_bf + ((row0 * HDIM + koff) ^ ((row0 & 7) << 3)));
                const int row1 = i0 + 16 + lrow;
                const bf16x8 a1 = *(const bf16x8*)(const void*)(h_bf + ((row1 * HDIM + koff) ^ ((row1 & 7) << 3)));
                acc0 = __builtin_amdgcn_mfma_f32_16x16x32_bf16(a0, bbV, acc0, 0, 0, 0);
                acc1 = __builtin_amdgcn_mfma_f32_16x16x32_bf16(a1, bbV, acc1, 0, 0, 0);
                zh0  = __builtin_amdgcn_mfma_f32_16x16x32_bf16(a0, bbZ, zh0,  0, 0, 0);
                zh1  = __builtin_amdgcn_mfma_f32_16x16x32_bf16(a1, bbZ, zh1,  0, 0, 0);
            }
        }
        if (isU) {
            // C-frag rows rt*16+lhi*4+r -> fp16 pairs at jp = rt*8+lhi*2 (+1)
            #pragma unroll
            for (int rt = 0; rt < 4; ++rt) {
                const f32x4& acc = rt == 0 ? acc0 : rt == 1 ? acc1 : rt == 2 ? acc2 : acc3;
                const int jp0 = rt * 8 + lhi * 2;
                u_pk[(jp0    ) * 129 + col] = cvt_pk(acc[0], acc[1]);
                u_pk[(jp0 + 1) * 129 + col] = cvt_pk(acc[2], acc[3]);
            }
        } else {
            #pragma unroll
            for (int r = 0; r < 4; ++r) {
                v_f32[( 0 + lhi * 4 + r) * 132 + col] = acc0[r];
                v_f32[(16 + lhi * 4 + r) * 132 + col] = acc1[r];
            }
        }
    }
    __syncthreads();

    // ---- Prefetch P4/P5 B-fragments (fp32) — latency hidden under P3's VALU ----
    // waves 0..7: mw2 (for P4); waves 8..15: dw1[H:] (for P5). Same ct = w&7.
    float pf[4][8];
    {
        const float* pw  = (w < 8) ? mw2 : dw1a;
        const int   colp = (w & 7) * 16 + lrow;
        #pragma unroll
        for (int kb = 0; kb < 4; ++kb)
            #pragma unroll
            for (int e = 0; e < 8; ++e)
                pf[kb][e] = pw[(kb * 32 + lhi * 8 + e) * HDIM + colp];
    }

    // ---- P3 (packed fp16 + dot2): r[ii][k] = sum_j A[j][ii]*relu(u[j][k]+v[ii][k]+mb1[k]) ----
    {
        const float bk = mb1[k];
        h2 vv[4];
        #pragma unroll
        for (int ii = 0; ii < 4; ++ii) {
            const float v = v_f32[(g * 4 + ii) * 132 + k] + bk;
            vv[ii] = cvt_pk(v, v);
        }
        const h2 zero2 = (h2)(_Float16)0;
        float racc[4] = {0.f, 0.f, 0.f, 0.f};
        #pragma unroll 4
        for (int jp = 0; jp < 32; ++jp) {
            const h2 up = u_pk[jp * 129 + k];
            const uint4 ap = *(const uint4*)&A_pk[jp][g * 4];   // wave-broadcast 16B
            const h2 p0 = __builtin_elementwise_max(up + vv[0], zero2);
            const h2 p1 = __builtin_elementwise_max(up + vv[1], zero2);
            const h2 p2 = __builtin_elementwise_max(up + vv[2], zero2);
            const h2 p3 = __builtin_elementwise_max(up + vv[3], zero2);
            racc[0] = __builtin_amdgcn_fdot2(p0, u2h(ap.x), racc[0], false);
            racc[1] = __builtin_amdgcn_fdot2(p1, u2h(ap.y), racc[1], false);
            racc[2] = __builtin_amdgcn_fdot2(p2, u2h(ap.z), racc[2], false);
            racc[3] = __builtin_amdgcn_fdot2(p3, u2h(ap.w), racc[3], false);
        }
        #pragma unroll
        for (int ii = 0; ii < 4; ++ii) {
            const int row = g * 4 + ii;
            r_bf[(row * HDIM + k) ^ ((row & 7) << 3)] = f2bf(racc[ii]);
        }
    }
    __syncthreads();

    // ---- convert prefetched fragments to bf16 (register-only) ----
    bf16x8 bfrag[4];
    #pragma unroll
    for (int kb = 0; kb < 4; ++kb) {
        union { bf16x8 v; unsigned short s[8]; } c;
        #pragma unroll
        for (int e = 0; e < 8; ++e) c.s[e] = f2bf(pf[kb][e]);
        bfrag[kb] = c.v;
    }

    // ---- P4 (MFMA, waves 0..7): agg[32][128] = r @ mw2 + Asum*mb2 -> bf16 LDS ----
    if (w < 8) {
        const int col = w * 16 + lrow;
        const float m2 = mb2[col];
        #pragma unroll
        for (int rt = 0; rt < 2; ++rt) {
            f32x4 acc = {0.f, 0.f, 0.f, 0.f};
            #pragma unroll
            for (int kb = 0; kb < 4; ++kb) {
                const int row = rt * 16 + lrow;
                const int eidx = (row * HDIM + kb * 32 + lhi * 8) ^ ((row & 7) << 3);
                const bf16x8 a = *(const bf16x8*)(const void*)(r_bf + eidx);
                acc = __builtin_amdgcn_mfma_f32_16x16x32_bf16(a, bfrag[kb], acc, 0, 0, 0);
            }
            #pragma unroll
            for (int r = 0; r < 4; ++r) {
                const int row = rt * 16 + lhi * 4 + r;
                agg_bf[(row * HDIM + col) ^ ((row & 7) << 3)] = f2bf(acc[r] + Asum[row] * m2);
            }
        }
    }
    __syncthreads();

    // ---- P5 (MFMA, waves 8..15): z = relu(zh + agg@dw1[H:] + db1) -> v_f32 (reused) ----
    if (w >= 8) {
        const int col = (w - 8) * 16 + lrow;
        f32x4 acc0 = zh0, acc1 = zh1;
        #pragma unroll
        for (int kb = 0; kb < 4; ++kb) {
            const int koff = kb * 32 + lhi * 8;
            const int row0 = lrow;
            const bf16x8 a0 = *(const bf16x8*)(const void*)(agg_bf + ((row0 * HDIM + koff) ^ ((row0 & 7) << 3)));
            acc0 = __builtin_amdgcn_mfma_f32_16x16x32_bf16(a0, bfrag[kb], acc0, 0, 0, 0);
            const int row1 = 16 + lrow;
            const bf16x8 a1 = *(const bf16x8*)(const void*)(agg_bf + ((row1 * HDIM + koff) ^ ((row1 & 7) << 3)));
            acc1 = __builtin_amdgcn_mfma_f32_16x16x32_bf16(a1, bfrag[kb], acc1, 0, 0, 0);
        }
        const float db = db1[col];
        #pragma unroll
        for (int r = 0; r < 4; ++r) {
            v_f32[( 0 + lhi * 4 + r) * 132 + col] = fmaxf(acc0[r] + db, 0.f);   // z
            v_f32[(16 + lhi * 4 + r) * 132 + col] = fmaxf(acc1[r] + db, 0.f);
        }
    }
    __syncthreads();

    // ---- P6: out[b][i0+row] = z[row] @ dw2 + db2 ----
    {
        const int row = tid >> 5;      // 0..31
        const int s   = tid & 31;
        float part = 0.0f;
        #pragma unroll
        for (int m = 0; m < 4; ++m) {
            const int kk = s + m * 32;
            part += v_f32[row * 132 + kk] * dw2[kk];
        }
        part += __shfl_xor(part, 1);
        part += __shfl_xor(part, 2);
        part += __shfl_xor(part, 4);
        part += __shfl_xor(part, 8);
        part += __shfl_xor(part, 16);
        if (s == 0) out[b * DVAR + i0 + row] = part + db2[0];
    }
}

extern "C" void kernel_launch(void* const* d_in, const int* in_sizes, int n_in,
                              void* d_out, int out_size, void* d_ws, size_t ws_size,
                              hipStream_t stream) {
    const float* X     = (const float*)d_in[0];
    const float* W     = (const float*)d_in[1];
    const float* enc_w = (const float*)d_in[2];
    const float* enc_b = (const float*)d_in[3];
    const float* mw1   = (const float*)d_in[4];
    const float* mb1   = (const float*)d_in[5];
    const float* mw2   = (const float*)d_in[6];
    const float* mb2   = (const float*)d_in[7];
    const float* dw1   = (const float*)d_in[8];
    const float* db1   = (const float*)d_in[9];
    const float* dw2   = (const float*)d_in[10];
    const float* db2   = (const float*)d_in[11];

    gnn_fused<<<dim3(BATCH * 2), dim3(NT), 0, stream>>>(
        X, W, enc_w, enc_b, mw1, mb1, mw2, mb2, dw1, db1, dw2, db2,
        (float*)d_out);
}

// Round 10
// 15.463 us; speedup vs baseline: 1.3924x; 1.0568x over previous
//
#include <hip/hip_runtime.h>

#define BATCH 128
#define DVAR  64
#define HDIM  128
#define NT    1024

typedef __attribute__((ext_vector_type(8))) __bf16    bf16x8;
typedef __attribute__((ext_vector_type(4))) float     f32x4;
typedef __attribute__((ext_vector_type(2))) _Float16  h2;

__device__ __forceinline__ unsigned short f2bf(float f) {
    unsigned u = __float_as_uint(f);
    u += 0x7FFF + ((u >> 16) & 1);          // round-to-nearest-even
    return (unsigned short)(u >> 16);
}
__device__ __forceinline__ h2 u2h(unsigned x) { union { unsigned u; h2 h; } c; c.u = x; return c.h; }
// v_cvt_pkrtz_f16_f32 returns a __fp16 vector; bit-cast to our _Float16 h2.
__device__ __forceinline__ h2 cvt_pk(float a, float b) {
    auto r = __builtin_amdgcn_cvt_pkrtz(a, b);
    union { decltype(r) f; h2 h; } c; c.f = r; return c.h;
}
// tanh(x) = 1 - 2/(e^{2x}+1); err ~1e-5 << fp16/bf16 quant
__device__ __forceinline__ float fast_tanh(float x) {
    const float e = __expf(2.0f * x);
    return fmaf(-2.0f, __builtin_amdgcn_rcpf(e + 1.0f), 1.0f);
}

// Pack 8 fp32 -> bf16x8 by TRUNCATION, 1 v_perm_b32 per pair (4 VALU total).
// v_perm_b32 sel: bytes 0-3 from src1, 4-7 from src0; we take bytes {2,3} of
// each fp32 (its high 16 bits). dst = {lo16=hi(x[2t]), hi16=hi(x[2t+1])}.
__device__ __forceinline__ bf16x8 pack8_trunc(const float* x) {
    union { bf16x8 v; unsigned u[4]; } r;
    #pragma unroll
    for (int t = 0; t < 4; ++t)
        r.u[t] = __builtin_amdgcn_perm(__float_as_uint(x[2 * t + 1]),
                                       __float_as_uint(x[2 * t]), 0x07060302u);
    return r.v;
}

// Gather one MFMA B-fragment (lane supplies B[kb*32+lhi*8+e][col]) from row-major
// fp32 [K][HDIM], truncation-packed to bf16. Weights are L2-resident.
__device__ __forceinline__ bf16x8 ld_bfrag(const float* __restrict__ B, int kb, int lhi, int col) {
    const float* p = B + (kb * 32 + lhi * 8) * HDIM + col;
    float t[8];
    #pragma unroll
    for (int e = 0; e < 8; ++e) t[e] = p[e * HDIM];
    return pack8_trunc(t);
}

// ---------------- single fused kernel ----------------
// Grid 256 = (b = blockIdx>>1, i0 = (blockIdx&1)*32), 1024 threads = 16 waves.
__global__ __launch_bounds__(NT, 4) void gnn_fused(
    const float* __restrict__ X,  const float* __restrict__ W,
    const float* __restrict__ enc_w, const float* __restrict__ enc_b,
    const float* __restrict__ mw1, const float* __restrict__ mb1,
    const float* __restrict__ mw2, const float* __restrict__ mb2,
    const float* __restrict__ dw1, const float* __restrict__ db1,
    const float* __restrict__ dw2, const float* __restrict__ db2,
    float* __restrict__ out)
{
    __shared__ unsigned short h_bf[DVAR * HDIM];   // 16 KB, XOR-swizzled (MFMA A)
    __shared__ h2             u_pk[32 * 129];      // 16.1 KB: (u[2jp],u[2jp+1]) fp16 pairs
    __shared__ float          v_f32[32 * 132];     // 16.5 KB, padded; reused as z
    __shared__ h2             A_pk[32][32];        // 4 KB: (A[2jp][ii],A[2jp+1][ii]) fp16
    __shared__ unsigned short r_bf[32 * HDIM];     // 8 KB, swizzled (MFMA A)
    __shared__ unsigned short agg_bf[32 * HDIM];   // 8 KB, swizzled (MFMA A)
    __shared__ float          Asum[32];

    const int tid  = threadIdx.x;
    const int b    = blockIdx.x >> 1;
    const int i0   = (blockIdx.x & 1) * 32;        // this block's i range [i0, i0+32)
    const int k    = tid & (HDIM - 1);
    const int g    = tid >> 7;          // 0..7, wave-uniform
    const int w    = tid >> 6;          // wave 0..15
    const int lane = tid & 63;
    const int lrow = lane & 15;
    const int lhi  = lane >> 4;

    const float* mw1v = mw1 + HDIM * HDIM;   // mw1[H:]
    const float* dw1a = dw1 + HDIM * HDIM;   // dw1[H:] (agg side)

    // ---- Pre-barrier prefetch: first 2 B-fragments (kb=0,1) of this wave's
    // primary P2 operand — L2 latency hides under P1's tanh. 16 VGPR.
    float pre[2][8];
    {
        const float* pb   = (w < 8) ? mw1 : mw1v;
        const int    colp = (w & 7) * 16 + lrow;
        #pragma unroll
        for (int kb = 0; kb < 2; ++kb)
            #pragma unroll
            for (int e = 0; e < 8; ++e)
                pre[kb][e] = pb[(kb * 32 + lhi * 8 + e) * HDIM + colp];
    }

    // ---- P1: h = tanh(X*enc_w+enc_b) -> bf16 LDS (swizzled); stage A fp16 pairs ----
    {
        const float ew = enc_w[k];
        const float eb = enc_b[k];
        #pragma unroll
        for (int m = 0; m < 8; ++m) {
            const int j = g + m * 8;                       // wave-uniform row
            h_bf[(j * HDIM + k) ^ ((j & 7) << 3)] = f2bf(fast_tanh(X[b * DVAR + j] * ew + eb));
        }
        const int jp = tid >> 5, ii = tid & 31;            // 32 jp-pairs x 32 ii
        const int i  = i0 + ii;
        const int j0 = 2 * jp, j1 = 2 * jp + 1;
        const float a0 = (j0 == i) ? 0.f : W[j0 * DVAR + i];
        const float a1 = (j1 == i) ? 0.f : W[j1 * DVAR + i];
        A_pk[jp][ii] = cvt_pk(a0, a1);
    }
    __syncthreads();
    if (tid < 32) {                                        // Asum[ii] = sum_j A[j,i]
        float s = 0.f;
        for (int jp = 0; jp < 32; ++jp) {
            const h2 a = A_pk[jp][tid];
            s += (float)a.x + (float)a.y;
        }
        Asum[tid] = s;
    }

    // ---- P2 (MFMA, column-jobs):
    //   waves 0..7 : u[64][128] = h @ mw1[:H]        -> u_pk fp16 pairs
    //   waves 8..15: v[32][128] = h[i0:] @ mw1[H:]   -> v_f32
    //              + zh[32][128] = h[i0:] @ dw1[:H]  (stashed in registers for P5)
    f32x4 zh0 = {0.f,0.f,0.f,0.f}, zh1 = {0.f,0.f,0.f,0.f};   // live P2 -> P5 (waves >= 8)
    {
        const bool isU = (w < 8);
        const int ct   = isU ? w : (w - 8);
        const int col  = ct * 16 + lrow;
        f32x4 acc0 = {0.f,0.f,0.f,0.f}, acc1 = {0.f,0.f,0.f,0.f};
        f32x4 acc2 = {0.f,0.f,0.f,0.f}, acc3 = {0.f,0.f,0.f,0.f};
        #pragma unroll
        for (int kb = 0; kb < 4; ++kb) {
            const int koff = kb * 32 + lhi * 8;
            if (isU) {
                const bf16x8 bb = (kb < 2) ? pack8_trunc(pre[kb]) : ld_bfrag(mw1, kb, lhi, col);
                #pragma unroll
                for (int rt = 0; rt < 4; ++rt) {
                    const int row = rt * 16 + lrow;
                    const bf16x8 a = *(const bf16x8*)(const void*)(h_bf + ((row * HDIM + koff) ^ ((row & 7) << 3)));
                    f32x4& acc = rt == 0 ? acc0 : rt == 1 ? acc1 : rt == 2 ? acc2 : acc3;
                    acc = __builtin_amdgcn_mfma_f32_16x16x32_bf16(a, bb, acc, 0, 0, 0);
                }
            } else {
                const bf16x8 bbV = (kb < 2) ? pack8_trunc(pre[kb]) : ld_bfrag(mw1v, kb, lhi, col);
                const bf16x8 bbZ = ld_bfrag(dw1, kb, lhi, col);
                const int row0 = i0 + lrow;
                const bf16x8 a0 = *(const bf16x8*)(const void*)(h_bf + ((row0 * HDIM + koff) ^ ((row0 & 7) << 3)));
                const int row1 = i0 + 16 + lrow;
                const bf16x8 a1 = *(const bf16x8*)(const void*)(h_bf + ((row1 * HDIM + koff) ^ ((row1 & 7) << 3)));
                acc0 = __builtin_amdgcn_mfma_f32_16x16x32_bf16(a0, bbV, acc0, 0, 0, 0);
                acc1 = __builtin_amdgcn_mfma_f32_16x16x32_bf16(a1, bbV, acc1, 0, 0, 0);
                zh0  = __builtin_amdgcn_mfma_f32_16x16x32_bf16(a0, bbZ, zh0,  0, 0, 0);
                zh1  = __builtin_amdgcn_mfma_f32_16x16x32_bf16(a1, bbZ, zh1,  0, 0, 0);
            }
        }
        if (isU) {
            // C-frag rows rt*16+lhi*4+r -> fp16 pairs at jp = rt*8+lhi*2 (+1)
            #pragma unroll
            for (int rt = 0; rt < 4; ++rt) {
                const f32x4& acc = rt == 0 ? acc0 : rt == 1 ? acc1 : rt == 2 ? acc2 : acc3;
                const int jp0 = rt * 8 + lhi * 2;
                u_pk[(jp0    ) * 129 + col] = cvt_pk(acc[0], acc[1]);
                u_pk[(jp0 + 1) * 129 + col] = cvt_pk(acc[2], acc[3]);
            }
        } else {
            #pragma unroll
            for (int r = 0; r < 4; ++r) {
                v_f32[( 0 + lhi * 4 + r) * 132 + col] = acc0[r];
                v_f32[(16 + lhi * 4 + r) * 132 + col] = acc1[r];
            }
        }
    }
    __syncthreads();

    // ---- Prefetch P4/P5 B-fragments (fp32) — latency hidden under P3's VALU ----
    // waves 0..7: mw2 (for P4); waves 8..15: dw1[H:] (for P5). Same ct = w&7.
    float pf[4][8];
    {
        const float* pw  = (w < 8) ? mw2 : dw1a;
        const int   colp = (w & 7) * 16 + lrow;
        #pragma unroll
        for (int kb = 0; kb < 4; ++kb)
            #pragma unroll
            for (int e = 0; e < 8; ++e)
                pf[kb][e] = pw[(kb * 32 + lhi * 8 + e) * HDIM + colp];
    }

    // ---- P3 (packed fp16 + dot2): r[ii][k] = sum_j A[j][ii]*relu(u[j][k]+v[ii][k]+mb1[k]) ----
    {
        const float bk = mb1[k];
        h2 vv[4];
        #pragma unroll
        for (int ii = 0; ii < 4; ++ii) {
            const float v = v_f32[(g * 4 + ii) * 132 + k] + bk;
            vv[ii] = cvt_pk(v, v);
        }
        const h2 zero2 = (h2)(_Float16)0;
        float racc[4] = {0.f, 0.f, 0.f, 0.f};
        #pragma unroll 8
        for (int jp = 0; jp < 32; ++jp) {
            const h2 up = u_pk[jp * 129 + k];
            const uint4 ap = *(const uint4*)&A_pk[jp][g * 4];   // wave-broadcast 16B
            const h2 p0 = __builtin_elementwise_max(up + vv[0], zero2);
            const h2 p1 = __builtin_elementwise_max(up + vv[1], zero2);
            const h2 p2 = __builtin_elementwise_max(up + vv[2], zero2);
            const h2 p3 = __builtin_elementwise_max(up + vv[3], zero2);
            racc[0] = __builtin_amdgcn_fdot2(p0, u2h(ap.x), racc[0], false);
            racc[1] = __builtin_amdgcn_fdot2(p1, u2h(ap.y), racc[1], false);
            racc[2] = __builtin_amdgcn_fdot2(p2, u2h(ap.z), racc[2], false);
            racc[3] = __builtin_amdgcn_fdot2(p3, u2h(ap.w), racc[3], false);
        }
        #pragma unroll
        for (int ii = 0; ii < 4; ++ii) {
            const int row = g * 4 + ii;
            r_bf[(row * HDIM + k) ^ ((row & 7) << 3)] = f2bf(racc[ii]);
        }
    }
    __syncthreads();

    // ---- convert prefetched fragments to bf16 (register-only, 4 perms each) ----
    bf16x8 bfrag[4];
    #pragma unroll
    for (int kb = 0; kb < 4; ++kb) bfrag[kb] = pack8_trunc(pf[kb]);

    // ---- P4 (MFMA, waves 0..7): agg[32][128] = r @ mw2 + Asum*mb2 -> bf16 LDS ----
    if (w < 8) {
        const int col = w * 16 + lrow;
        const float m2 = mb2[col];
        #pragma unroll
        for (int rt = 0; rt < 2; ++rt) {
            f32x4 acc = {0.f, 0.f, 0.f, 0.f};
            #pragma unroll
            for (int kb = 0; kb < 4; ++kb) {
                const int row = rt * 16 + lrow;
                const int eidx = (row * HDIM + kb * 32 + lhi * 8) ^ ((row & 7) << 3);
                const bf16x8 a = *(const bf16x8*)(const void*)(r_bf + eidx);
                acc = __builtin_amdgcn_mfma_f32_16x16x32_bf16(a, bfrag[kb], acc, 0, 0, 0);
            }
            #pragma unroll
            for (int r = 0; r < 4; ++r) {
                const int row = rt * 16 + lhi * 4 + r;
                agg_bf[(row * HDIM + col) ^ ((row & 7) << 3)] = f2bf(acc[r] + Asum[row] * m2);
            }
        }
    }
    __syncthreads();

    // ---- P5 (MFMA, waves 8..15): z = relu(zh + agg@dw1[H:] + db1) -> v_f32 (reused) ----
    if (w >= 8) {
        const int col = (w - 8) * 16 + lrow;
        f32x4 acc0 = zh0, acc1 = zh1;
        #pragma unroll
        for (int kb = 0; kb < 4; ++kb) {
            const int koff = kb * 32 + lhi * 8;
            const int row0 = lrow;
            const bf16x8 a0 = *(const bf16x8*)(const void*)(agg_bf + ((row0 * HDIM + koff) ^ ((row0 & 7) << 3)));
            acc0 = __builtin_amdgcn_mfma_f32_16x16x32_bf16(a0, bfrag[kb], acc0, 0, 0, 0);
            const int row1 = 16 + lrow;
            const bf16x8 a1 = *(const bf16x8*)(const void*)(agg_bf + ((row1 * HDIM + koff) ^ ((row1 & 7) << 3)));
            acc1 = __builtin_amdgcn_mfma_f32_16x16x32_bf16(a1, bfrag[kb], acc1, 0, 0, 0);
        }
        const float db = db1[col];
        #pragma unroll
        for (int r = 0; r < 4; ++r) {
            v_f32[( 0 + lhi * 4 + r) * 132 + col] = fmaxf(acc0[r] + db, 0.f);   // z
            v_f32[(16 + lhi * 4 + r) * 132 + col] = fmaxf(acc1[r] + db, 0.f);
        }
    }
    __syncthreads();

    // ---- P6: out[b][i0+row] = z[row] @ dw2 + db2 ----
    {
        const int row = tid >> 5;      // 0..31
        const int s   = tid & 31;
        float part = 0.0f;
        #pragma unroll
        for (int m = 0; m < 4; ++m) {
            const int kk = s + m * 32;
            part += v_f32[row * 132 + kk] * dw2[kk];
        }
        part += __shfl_xor(part, 1);
        part += __shfl_xor(part, 2);
        part += __shfl_xor(part, 4);
        part += __shfl_xor(part, 8);
        part += __shfl_xor(part, 16);
        if (s == 0) out[b * DVAR + i0 + row] = part + db2[0];
    }
}

extern "C" void kernel_launch(void* const* d_in, const int* in_sizes, int n_in,
                              void* d_out, int out_size, void* d_ws, size_t ws_size,
                              hipStream_t stream) {
    const float* X     = (const float*)d_in[0];
    const float* W     = (const float*)d_in[1];
    const float* enc_w = (const float*)d_in[2];
    const float* enc_b = (const float*)d_in[3];
    const float* mw1   = (const float*)d_in[4];
    const float* mb1   = (const float*)d_in[5];
    const float* mw2   = (const float*)d_in[6];
    const float* mb2   = (const float*)d_in[7];
    const float* dw1   = (const float*)d_in[8];
    const float* db1   = (const float*)d_in[9];
    const float* dw2   = (const float*)d_in[10];
    const float* db2   = (const float*)d_in[11];

    gnn_fused<<<dim3(BATCH * 2), dim3(NT), 0, stream>>>(
        X, W, enc_w, enc_b, mw1, mb1, mw2, mb2, dw1, db1, dw2, db2,
        (float*)d_out);
}